// Round 16
// baseline (93.661 us; speedup 1.0000x reference)
//
#include <hip/hip_runtime.h>
#include <math.h>

// ---------------------------------------------------------------------------
// Chamfer distance via MFMA (gfx950) — round 16: 8 waves/SIMD (max TLP).
//
// d2(p,g) = p^2 + g^2 - 2 p.g computed entirely inside
// v_mfma_f32_32x32x16_bf16 via bf16 hi/lo (Dekker) split over K=16 slots
// (HW-verified absmax 0.0, rounds 1-15).
//
// r12-r15: protocol removal, prefetch, and ILP all null; r11 showed the
// allocator collapses parallel acc sets (ILP unobtainable from source). The
// surviving model: the ~300cy per-iteration chain (L2 load -> MFMA -> tree16)
// must be hidden by TLP, and every config so far ran only ~4 waves/SIMD
// (4 x ~70cy issue < 300cy chain -> pipes serialize). 8 waves/SIMD tips it:
// 8 x ~40cy = 320 >= 300.
// This round: BLOCK=256 (4 waves, the proven 2-chain spill-free body),
// COLS_PER_BLOCK=64 (2 reg-resident B frags), row-split 4 ->
// grid (256,4,2) = 2048 blocks = 8 blocks/CU = 32 waves/CU = 8 waves/SIMD.
// Tiny LDS (256+ B). Col-mins -> LDS -> global atomicMin (protocol ~free,
// r13-proven); finalize = r12's separate reader dispatch.
// Tripwires: VGPR <= 64, WRITE <= 8 MB (deterministic tens-of-MB = spill).
// ---------------------------------------------------------------------------

constexpr int NPTS  = 16384;
constexpr int BLOCK = 256;                        // 4 waves
constexpr int WAVES = BLOCK / 64;

constexpr int COLS_PER_BLOCK = 64;                // 2 x 32-col groups, in regs
constexpr int NCB = NPTS / COLS_PER_BLOCK;        // 256 col-blocks
constexpr int RSLICES = 4;                        // row-split
constexpr int ROWS_PER_SLICE = NPTS / RSLICES;    // 4096
constexpr int ROWS_PER_WAVE = ROWS_PER_SLICE / WAVES;   // 1024
constexpr int ATILES = ROWS_PER_WAVE / 32;        // 32 iterations

typedef __attribute__((ext_vector_type(8)))  __bf16 bf16x8;
typedef __attribute__((ext_vector_type(16))) float  f32x16;

__device__ inline unsigned short f2bf(float f) {          // RNE float->bf16
    unsigned u = __float_as_uint(f);
    u += 0x7FFFu + ((u >> 16) & 1u);
    return (unsigned short)(u >> 16);
}
__device__ inline float bf2f(unsigned short h) {
    return __uint_as_float(((unsigned)h) << 16);
}
__device__ inline unsigned pk(unsigned short lo, unsigned short hi) {
    return (unsigned)lo | ((unsigned)hi << 16);
}

// ---------------------------------------------------------------------------
// Fragment layouts (HW-verified pairing, rounds 1-15). For vector v with norm
// s (split hi/lo), slot sum of A(v,s) . B(w,t) = v.w + s + t:
//   A half0: [vhx,vhy,vhz, vlx,vly,vlz, vhx,vhy]
//   A half1: [vhz, s_h, s_l, 1, 1, vlx, vly, vlz]
//   B half0: [whx,why,whz, whx,why,whz, wlx,wly]
//   B half1: [wlz, 1, 1, t_h, t_l, wlx, wly, wlz]
// Pass 0: A(p,p2) . B(-2g,g2) = d2 -> per-gt-col min -> minG.
// Pass 1: A(-2g,g2) . B(p,p2) = d2 -> per-pred-col min -> minP.
// Arrays (half-major, X[half*NPTS+i]):
//   Af = A-layout(p,p2)    Bf = B-layout(-2g,g2)
//   Ag = A-layout(-2g,g2)  Bp = B-layout(p,p2)
// ---------------------------------------------------------------------------
__global__ __launch_bounds__(256) void pack_init_kernel(
    const float* __restrict__ pred, const float* __restrict__ gt,
    uint4* __restrict__ Af, uint4* __restrict__ Bf,
    uint4* __restrict__ Ag, uint4* __restrict__ Bp,
    unsigned int* __restrict__ minP, unsigned int* __restrict__ minG)
{
    const unsigned short ONE = 0x3F80;
    int i = blockIdx.x * 256 + threadIdx.x;
    if (i >= NPTS) return;

    {   // pred: split p, p2
        float x = pred[3*i], y = pred[3*i+1], z = pred[3*i+2];
        unsigned short hx = f2bf(x), hy = f2bf(y), hz = f2bf(z);
        unsigned short lx = f2bf(x - bf2f(hx));
        unsigned short ly = f2bf(y - bf2f(hy));
        unsigned short lz = f2bf(z - bf2f(hz));
        float p2 = fmaf(x, x, fmaf(y, y, z * z));
        unsigned short sh = f2bf(p2), sl = f2bf(p2 - bf2f(sh));
        uint4 a0, a1, b0, b1;
        a0.x = pk(hx, hy); a0.y = pk(hz, lx); a0.z = pk(ly, lz); a0.w = pk(hx, hy);
        a1.x = pk(hz, sh); a1.y = pk(sl, ONE); a1.z = pk(ONE, lx); a1.w = pk(ly, lz);
        b0.x = pk(hx, hy); b0.y = pk(hz, hx); b0.z = pk(hy, hz); b0.w = pk(lx, ly);
        b1.x = pk(lz, ONE); b1.y = pk(ONE, sh); b1.z = pk(sl, lx); b1.w = pk(ly, lz);
        Af[i] = a0; Af[NPTS + i] = a1;
        Bp[i] = b0; Bp[NPTS + i] = b1;
    }
    {   // gt: split m = -2g, g2
        float gx = gt[3*i], gy = gt[3*i+1], gz = gt[3*i+2];
        float mx = -2.0f * gx, my = -2.0f * gy, mz = -2.0f * gz;
        unsigned short hx = f2bf(mx), hy = f2bf(my), hz = f2bf(mz);
        unsigned short lx = f2bf(mx - bf2f(hx));
        unsigned short ly = f2bf(my - bf2f(hy));
        unsigned short lz = f2bf(mz - bf2f(hz));
        float g2 = fmaf(gx, gx, fmaf(gy, gy, gz * gz));
        unsigned short sh = f2bf(g2), sl = f2bf(g2 - bf2f(sh));
        uint4 a0, a1, b0, b1;
        a0.x = pk(hx, hy); a0.y = pk(hz, lx); a0.z = pk(ly, lz); a0.w = pk(hx, hy);
        a1.x = pk(hz, sh); a1.y = pk(sl, ONE); a1.z = pk(ONE, lx); a1.w = pk(ly, lz);
        b0.x = pk(hx, hy); b0.y = pk(hz, hx); b0.z = pk(hy, hz); b0.w = pk(lx, ly);
        b1.x = pk(lz, ONE); b1.y = pk(ONE, sh); b1.z = pk(sl, lx); b1.w = pk(ly, lz);
        Ag[i] = a0; Ag[NPTS + i] = a1;
        Bf[i] = b0; Bf[NPTS + i] = b1;
    }
    minP[i] = 0x7F800000u;   // +inf
    minG[i] = 0x7F800000u;
}

__device__ inline float tree16(const f32x16 a) {   // min of 16 (v_min3 tree)
    float m0 = fminf(fminf(a[0],  a[1]),  a[2]);
    float m1 = fminf(fminf(a[3],  a[4]),  a[5]);
    float m2 = fminf(fminf(a[6],  a[7]),  a[8]);
    float m3 = fminf(fminf(a[9],  a[10]), a[11]);
    float m4 = fminf(fminf(a[12], a[13]), a[14]);
    float m5 = fminf(fminf(m0, m1), m2);
    float m6 = fminf(fminf(m3, m4), a[15]);
    return fminf(m5, m6);
}

// ---------------------------------------------------------------------------
// Main kernel: grid (256, 4, 2); block = 64 B-cols x 4096 A-rows, 4 waves.
// blockIdx.z picks the pass, blockIdx.y the row slice. Wave wv streams rows
// [slice*4096 + wv*1024, +1024). 2 B fragments register-resident. C/D layout
// (HW-verified): col = lane&31, row = (reg&3)+8*(reg>>2)+4*(lane>>5).
// tree16 + k-half shfl + LDS combine -> per-block col-min -> global atomicMin.
// ---------------------------------------------------------------------------
__global__ __launch_bounds__(BLOCK) void chamfer_mfma_kernel(
    const uint4* __restrict__ Af, const uint4* __restrict__ Bf,
    const uint4* __restrict__ Ag, const uint4* __restrict__ Bp,
    unsigned int* __restrict__ minP, unsigned int* __restrict__ minG)
{
    const int tid  = threadIdx.x;
    const int wv   = tid >> 6;
    const int lane = tid & 63;
    const int half = lane >> 5;
    const int ln31 = lane & 31;

    const uint4* __restrict__ Aside;
    const uint4* __restrict__ Bside;
    unsigned int* __restrict__ outMin;
    if (blockIdx.z == 0) { Aside = Af; Bside = Bf; outMin = minG; }
    else                 { Aside = Ag; Bside = Bp; outMin = minP; }

    const int colBase = blockIdx.x * COLS_PER_BLOCK;
    const int rowBase = blockIdx.y * ROWS_PER_SLICE + wv * ROWS_PER_WAVE;

    // B fragments: register-resident, loaded once (2 col-groups).
    const uint4* __restrict__ Bh = Bside + half * NPTS + colBase;
    bf16x8 bf0 = __builtin_bit_cast(bf16x8, Bh[ln31]);
    bf16x8 bf1 = __builtin_bit_cast(bf16x8, Bh[32 + ln31]);

    // Wave's A slice (1024 rows = 32 tiles), streamed from L2.
    const uint4* __restrict__ Ah = Aside + half * NPTS + rowBase;

    const f32x16 zacc = {0.f,0.f,0.f,0.f, 0.f,0.f,0.f,0.f,
                         0.f,0.f,0.f,0.f, 0.f,0.f,0.f,0.f};

    float rm0 = INFINITY, rm1 = INFINITY;

    #pragma unroll 2
    for (int t = 0; t < ATILES; ++t) {
        bf16x8 af = __builtin_bit_cast(bf16x8, Ah[t * 32 + ln31]);
        f32x16 a0 = __builtin_amdgcn_mfma_f32_32x32x16_bf16(af, bf0, zacc, 0, 0, 0);
        f32x16 a1 = __builtin_amdgcn_mfma_f32_32x32x16_bf16(af, bf1, zacc, 0, 0, 0);
        rm0 = fminf(rm0, tree16(a0));
        rm1 = fminf(rm1, tree16(a1));
    }

    // Combine the two k-halves (same col, disjoint row subsets).
    rm0 = fminf(rm0, __shfl_xor(rm0, 32, 64));
    rm1 = fminf(rm1, __shfl_xor(rm1, 32, 64));

    // Cross-wave combine: 64-entry LDS min array (once per block).
    __shared__ unsigned int cmin[COLS_PER_BLOCK];
    if (tid < COLS_PER_BLOCK) cmin[tid] = 0x7F800000u;
    __syncthreads();
    if (half == 0) {
        atomicMin(&cmin[ln31],      __float_as_uint(fmaxf(rm0, 0.0f)));
        atomicMin(&cmin[32 + ln31], __float_as_uint(fmaxf(rm1, 0.0f)));
    }
    __syncthreads();

    // Merge this block's partial col-mins into the global array.
    if (tid < COLS_PER_BLOCK)
        atomicMin(&outMin[colBase + tid], cmin[tid]);   // already clamped >= 0
    // No drain/ticket: end-of-dispatch release + stream order covers finalize.
}

// ---------------------------------------------------------------------------
// Finalize: 1 block x 1024 threads; plain loads (stream-ordered visibility).
// ---------------------------------------------------------------------------
__global__ __launch_bounds__(1024) void finalize_kernel(
    const unsigned int* __restrict__ minP,
    const unsigned int* __restrict__ minG,
    const float* __restrict__ wpred, const float* __restrict__ wgt,
    float* __restrict__ out)
{
    const int tid  = threadIdx.x;
    const int lane = tid & 63;
    const int wv   = tid >> 6;

    float np = 0.f, dp = 0.f, ng = 0.f, dg = 0.f;
    #pragma unroll 4
    for (int i = tid; i < NPTS; i += 1024) {
        float v = __uint_as_float(minP[i]);
        float w = wpred[i];
        np = fmaf(w, v, np); dp += w;
        float u = __uint_as_float(minG[i]);
        float x = wgt[i];
        ng = fmaf(x, u, ng); dg += x;
    }
    #pragma unroll
    for (int off = 1; off < 64; off <<= 1) {
        np += __shfl_xor(np, off, 64);
        dp += __shfl_xor(dp, off, 64);
        ng += __shfl_xor(ng, off, 64);
        dg += __shfl_xor(dg, off, 64);
    }
    __shared__ float sred[4][16];
    if (lane == 0) { sred[0][wv] = np; sred[1][wv] = dp;
                     sred[2][wv] = ng; sred[3][wv] = dg; }
    __syncthreads();
    if (tid == 0) {
        float NP = 0.f, DP = 0.f, NG = 0.f, DG = 0.f;
        #pragma unroll
        for (int k = 0; k < 16; ++k) {
            NP += sred[0][k]; DP += sred[1][k];
            NG += sred[2][k]; DG += sred[3][k];
        }
        out[0] = NP / fmaxf(DP, 1e-9f) + NG / fmaxf(DG, 1e-9f);
    }
}

// ---------------------------------------------------------------------------
extern "C" void kernel_launch(void* const* d_in, const int* in_sizes, int n_in,
                              void* d_out, int out_size, void* d_ws, size_t ws_size,
                              hipStream_t stream)
{
    const float* pred  = (const float*)d_in[0];   // (P,3)
    const float* gt    = (const float*)d_in[1];   // (G,3)
    const float* wpred = (const float*)d_in[2];   // (P,)
    const float* wgt   = (const float*)d_in[3];   // (G,)
    float* out = (float*)d_out;

    // ws: Af|Bf|Ag|Bp (512K each) | minP(64K) | minG(64K)  (~2.13 MB)
    uint4* Af = (uint4*)d_ws;
    uint4* Bf = Af + 2 * NPTS;
    uint4* Ag = Bf + 2 * NPTS;
    uint4* Bp = Ag + 2 * NPTS;
    unsigned int* minP = (unsigned int*)(Bp + 2 * NPTS);
    unsigned int* minG = minP + NPTS;

    pack_init_kernel<<<NPTS / 256, 256, 0, stream>>>(
        pred, gt, Af, Bf, Ag, Bp, minP, minG);

    chamfer_mfma_kernel<<<dim3(NCB, RSLICES, 2), BLOCK, 0, stream>>>(
        Af, Bf, Ag, Bp, minP, minG);

    finalize_kernel<<<1, 1024, 0, stream>>>(minP, minG, wpred, wgt, out);
}

// Round 17
// 81.477 us; speedup vs baseline: 1.1495x; 1.1495x over previous
//
#include <hip/hip_runtime.h>
#include <math.h>

// ---------------------------------------------------------------------------
// Chamfer distance via MFMA (gfx950) — round 17: revert to r15 (best measured).
//
// d2(p,g) = p^2 + g^2 - 2 p.g computed entirely inside
// v_mfma_f32_32x32x16_bf16 via bf16 hi/lo (Dekker) split over K=16 slots
// (HW-verified absmax 0.0, rounds 1-16).
//
// Final landscape (rounds 9-16): wall tracks BLOCK COUNT (~6-8us per extra
// 1024 blocks of non-overlapped block head/tail), not loop issue. Protocol
// removal (r12/13), prefetch (r14), ILP (r11/15), max-TLP (r16: REGRESSED
// +12us) are all null on the loop. r15's 256 blocks = exactly 1/CU is the
// optimum of the block-count curve; fewer would idle CUs. Remaining total:
// ~41us harness re-poison fill (82% HBM peak, itself memory-roofline),
// ~25us chamfer (all levers exhausted), ~4us pack+finalize, ~8us gaps.
// This file is r15 byte-for-byte.
// ---------------------------------------------------------------------------

constexpr int NPTS  = 16384;
constexpr int BLOCK = 1024;                       // 16 waves
constexpr int WAVES = BLOCK / 64;

constexpr int COLS_PER_BLOCK = 128;               // 4 x 32-col groups, in regs
constexpr int NCB = NPTS / COLS_PER_BLOCK;        // 128 col-blocks per pass
constexpr int ROWS_PER_WAVE = NPTS / WAVES;       // 1024
constexpr int ATILES = ROWS_PER_WAVE / 32;        // 32 iterations

typedef __attribute__((ext_vector_type(8)))  __bf16 bf16x8;
typedef __attribute__((ext_vector_type(16))) float  f32x16;

__device__ inline unsigned short f2bf(float f) {          // RNE float->bf16
    unsigned u = __float_as_uint(f);
    u += 0x7FFFu + ((u >> 16) & 1u);
    return (unsigned short)(u >> 16);
}
__device__ inline float bf2f(unsigned short h) {
    return __uint_as_float(((unsigned)h) << 16);
}
__device__ inline unsigned pk(unsigned short lo, unsigned short hi) {
    return (unsigned)lo | ((unsigned)hi << 16);
}

// ---------------------------------------------------------------------------
// Fragment layouts (HW-verified pairing, rounds 1-16). For vector v with norm
// s (split hi/lo), slot sum of A(v,s) . B(w,t) = v.w + s + t:
//   A half0: [vhx,vhy,vhz, vlx,vly,vlz, vhx,vhy]
//   A half1: [vhz, s_h, s_l, 1, 1, vlx, vly, vlz]
//   B half0: [whx,why,whz, whx,why,whz, wlx,wly]
//   B half1: [wlz, 1, 1, t_h, t_l, wlx, wly, wlz]
// Pass 0: A(p,p2) . B(-2g,g2) = d2 -> per-gt-col min (weights wgt).
// Pass 1: A(-2g,g2) . B(p,p2) = d2 -> per-pred-col min (weights wpred).
// Arrays (half-major, X[half*NPTS+i]):
//   Af = A-layout(p,p2)    Bf = B-layout(-2g,g2)
//   Ag = A-layout(-2g,g2)  Bp = B-layout(p,p2)
// ---------------------------------------------------------------------------
__global__ __launch_bounds__(256) void pack_init_kernel(
    const float* __restrict__ pred, const float* __restrict__ gt,
    uint4* __restrict__ Af, uint4* __restrict__ Bf,
    uint4* __restrict__ Ag, uint4* __restrict__ Bp)
{
    const unsigned short ONE = 0x3F80;
    int i = blockIdx.x * 256 + threadIdx.x;
    if (i >= NPTS) return;

    {   // pred: split p, p2
        float x = pred[3*i], y = pred[3*i+1], z = pred[3*i+2];
        unsigned short hx = f2bf(x), hy = f2bf(y), hz = f2bf(z);
        unsigned short lx = f2bf(x - bf2f(hx));
        unsigned short ly = f2bf(y - bf2f(hy));
        unsigned short lz = f2bf(z - bf2f(hz));
        float p2 = fmaf(x, x, fmaf(y, y, z * z));
        unsigned short sh = f2bf(p2), sl = f2bf(p2 - bf2f(sh));
        uint4 a0, a1, b0, b1;
        a0.x = pk(hx, hy); a0.y = pk(hz, lx); a0.z = pk(ly, lz); a0.w = pk(hx, hy);
        a1.x = pk(hz, sh); a1.y = pk(sl, ONE); a1.z = pk(ONE, lx); a1.w = pk(ly, lz);
        b0.x = pk(hx, hy); b0.y = pk(hz, hx); b0.z = pk(hy, hz); b0.w = pk(lx, ly);
        b1.x = pk(lz, ONE); b1.y = pk(ONE, sh); b1.z = pk(sl, lx); b1.w = pk(ly, lz);
        Af[i] = a0; Af[NPTS + i] = a1;
        Bp[i] = b0; Bp[NPTS + i] = b1;
    }
    {   // gt: split m = -2g, g2
        float gx = gt[3*i], gy = gt[3*i+1], gz = gt[3*i+2];
        float mx = -2.0f * gx, my = -2.0f * gy, mz = -2.0f * gz;
        unsigned short hx = f2bf(mx), hy = f2bf(my), hz = f2bf(mz);
        unsigned short lx = f2bf(mx - bf2f(hx));
        unsigned short ly = f2bf(my - bf2f(hy));
        unsigned short lz = f2bf(mz - bf2f(hz));
        float g2 = fmaf(gx, gx, fmaf(gy, gy, gz * gz));
        unsigned short sh = f2bf(g2), sl = f2bf(g2 - bf2f(sh));
        uint4 a0, a1, b0, b1;
        a0.x = pk(hx, hy); a0.y = pk(hz, lx); a0.z = pk(ly, lz); a0.w = pk(hx, hy);
        a1.x = pk(hz, sh); a1.y = pk(sl, ONE); a1.z = pk(ONE, lx); a1.w = pk(ly, lz);
        b0.x = pk(hx, hy); b0.y = pk(hz, hx); b0.z = pk(hy, hz); b0.w = pk(lx, ly);
        b1.x = pk(lz, ONE); b1.y = pk(ONE, sh); b1.z = pk(sl, lx); b1.w = pk(ly, lz);
        Ag[i] = a0; Ag[NPTS + i] = a1;
        Bf[i] = b0; Bf[NPTS + i] = b1;
    }
}

__device__ inline float tree16(const f32x16 a) {   // min of 16 (v_min3 tree)
    float m0 = fminf(fminf(a[0],  a[1]),  a[2]);
    float m1 = fminf(fminf(a[3],  a[4]),  a[5]);
    float m2 = fminf(fminf(a[6],  a[7]),  a[8]);
    float m3 = fminf(fminf(a[9],  a[10]), a[11]);
    float m4 = fminf(fminf(a[12], a[13]), a[14]);
    float m5 = fminf(fminf(m0, m1), m2);
    float m6 = fminf(fminf(m3, m4), a[15]);
    return fminf(m5, m6);
}

// ---------------------------------------------------------------------------
// Main kernel: grid (128, 2); block = 128 B-cols x all 16384 A-rows, 16 waves.
// blockIdx.y picks the pass. Wave wv streams rows [wv*1024, wv*1024+1024).
// 4 B fragments register-resident; per A-load the wave runs 4 independent
// MFMA->tree16->fmin chains. C/D layout (HW-verified): col = lane&31,
// row = (reg&3)+8*(reg>>2)+4*(lane>>5). End: 128-entry LDS combine (once),
// block owns complete col-mins -> weighted partial -> one float2 store.
// ---------------------------------------------------------------------------
__global__ __launch_bounds__(BLOCK) void chamfer_mfma_kernel(
    const uint4* __restrict__ Af, const uint4* __restrict__ Bf,
    const uint4* __restrict__ Ag, const uint4* __restrict__ Bp,
    const float* __restrict__ wpred, const float* __restrict__ wgt,
    float2* __restrict__ partials)
{
    const int tid  = threadIdx.x;
    const int wv   = tid >> 6;
    const int lane = tid & 63;
    const int half = lane >> 5;
    const int ln31 = lane & 31;

    const uint4* __restrict__ Aside;
    const uint4* __restrict__ Bside;
    const float* __restrict__ w;
    if (blockIdx.y == 0) { Aside = Af; Bside = Bf; w = wgt;   }
    else                 { Aside = Ag; Bside = Bp; w = wpred; }

    const int colBase = blockIdx.x * COLS_PER_BLOCK;

    // B fragments: register-resident, loaded once (4 col-groups).
    const uint4* __restrict__ Bh = Bside + half * NPTS + colBase;
    bf16x8 bf0 = __builtin_bit_cast(bf16x8, Bh[ln31]);
    bf16x8 bf1 = __builtin_bit_cast(bf16x8, Bh[32 + ln31]);
    bf16x8 bf2 = __builtin_bit_cast(bf16x8, Bh[64 + ln31]);
    bf16x8 bf3 = __builtin_bit_cast(bf16x8, Bh[96 + ln31]);

    // Wave's A slice (1024 rows = 32 tiles), streamed from L2.
    const uint4* __restrict__ Ah = Aside + half * NPTS + wv * ROWS_PER_WAVE;

    const f32x16 zacc = {0.f,0.f,0.f,0.f, 0.f,0.f,0.f,0.f,
                         0.f,0.f,0.f,0.f, 0.f,0.f,0.f,0.f};

    float rm0 = INFINITY, rm1 = INFINITY, rm2 = INFINITY, rm3 = INFINITY;

    #pragma unroll 2
    for (int t = 0; t < ATILES; ++t) {
        bf16x8 af = __builtin_bit_cast(bf16x8, Ah[t * 32 + ln31]);
        f32x16 a0 = __builtin_amdgcn_mfma_f32_32x32x16_bf16(af, bf0, zacc, 0, 0, 0);
        f32x16 a1 = __builtin_amdgcn_mfma_f32_32x32x16_bf16(af, bf1, zacc, 0, 0, 0);
        f32x16 a2 = __builtin_amdgcn_mfma_f32_32x32x16_bf16(af, bf2, zacc, 0, 0, 0);
        f32x16 a3 = __builtin_amdgcn_mfma_f32_32x32x16_bf16(af, bf3, zacc, 0, 0, 0);
        rm0 = fminf(rm0, tree16(a0));
        rm1 = fminf(rm1, tree16(a1));
        rm2 = fminf(rm2, tree16(a2));
        rm3 = fminf(rm3, tree16(a3));
    }

    // Combine the two k-halves (same col, disjoint row subsets).
    rm0 = fminf(rm0, __shfl_xor(rm0, 32, 64));
    rm1 = fminf(rm1, __shfl_xor(rm1, 32, 64));
    rm2 = fminf(rm2, __shfl_xor(rm2, 32, 64));
    rm3 = fminf(rm3, __shfl_xor(rm3, 32, 64));

    // Cross-wave combine: 128-entry LDS min array (once per block).
    __shared__ unsigned int cmin[COLS_PER_BLOCK];
    if (tid < COLS_PER_BLOCK) cmin[tid] = 0x7F800000u;
    __syncthreads();
    if (half == 0) {
        atomicMin(&cmin[ln31],      __float_as_uint(fmaxf(rm0, 0.0f)));
        atomicMin(&cmin[32 + ln31], __float_as_uint(fmaxf(rm1, 0.0f)));
        atomicMin(&cmin[64 + ln31], __float_as_uint(fmaxf(rm2, 0.0f)));
        atomicMin(&cmin[96 + ln31], __float_as_uint(fmaxf(rm3, 0.0f)));
    }
    __syncthreads();

    // Block owns the complete min for its 128 cols: weighted partial sums.
    __shared__ float psum[2][2];
    if (tid < COLS_PER_BLOCK) {
        float v  = __uint_as_float(cmin[tid]);
        float wc = w[colBase + tid];
        float num = wc * v;
        float den = wc;
        #pragma unroll
        for (int off = 1; off < 64; off <<= 1) {
            num += __shfl_xor(num, off, 64);
            den += __shfl_xor(den, off, 64);
        }
        if (lane == 0) { psum[tid >> 6][0] = num; psum[tid >> 6][1] = den; }
    }
    __syncthreads();
    if (tid == 0) {
        partials[blockIdx.y * NCB + blockIdx.x] =
            make_float2(psum[0][0] + psum[1][0], psum[0][1] + psum[1][1]);
    }
}

// ---------------------------------------------------------------------------
// Finalize: 1 block x 128 threads; deterministic reduce of 2x128 partials.
// Prior dispatch's stores are visible via stream order.
// ---------------------------------------------------------------------------
__global__ __launch_bounds__(128) void finalize_kernel(
    const float2* __restrict__ partials, float* __restrict__ out)
{
    const int tid  = threadIdx.x;
    const int lane = tid & 63;
    const int wv   = tid >> 6;

    float2 p0 = partials[tid];         // pass 0 (gt direction)
    float2 p1 = partials[NCB + tid];   // pass 1 (pred direction)
    float ng = p0.x, dg = p0.y, np = p1.x, dp = p1.y;

    #pragma unroll
    for (int off = 1; off < 64; off <<= 1) {
        ng += __shfl_xor(ng, off, 64);
        dg += __shfl_xor(dg, off, 64);
        np += __shfl_xor(np, off, 64);
        dp += __shfl_xor(dp, off, 64);
    }
    __shared__ float sred[4][2];
    if (lane == 0) { sred[0][wv] = ng; sred[1][wv] = dg;
                     sred[2][wv] = np; sred[3][wv] = dp; }
    __syncthreads();
    if (tid == 0) {
        float NG = sred[0][0] + sred[0][1];
        float DG = sred[1][0] + sred[1][1];
        float NP = sred[2][0] + sred[2][1];
        float DP = sred[3][0] + sred[3][1];
        out[0] = NP / fmaxf(DP, 1e-9f) + NG / fmaxf(DG, 1e-9f);
    }
}

// ---------------------------------------------------------------------------
extern "C" void kernel_launch(void* const* d_in, const int* in_sizes, int n_in,
                              void* d_out, int out_size, void* d_ws, size_t ws_size,
                              hipStream_t stream)
{
    const float* pred  = (const float*)d_in[0];   // (P,3)
    const float* gt    = (const float*)d_in[1];   // (G,3)
    const float* wpred = (const float*)d_in[2];   // (P,)
    const float* wgt   = (const float*)d_in[3];   // (G,)
    float* out = (float*)d_out;

    // ws: Af|Bf|Ag|Bp (512K each) | partials (2x128 float2 = 2 KB)
    uint4* Af = (uint4*)d_ws;
    uint4* Bf = Af + 2 * NPTS;
    uint4* Ag = Bf + 2 * NPTS;
    uint4* Bp = Ag + 2 * NPTS;
    float2* partials = (float2*)(Bp + 2 * NPTS);

    pack_init_kernel<<<NPTS / 256, 256, 0, stream>>>(
        pred, gt, Af, Bf, Ag, Bp);

    chamfer_mfma_kernel<<<dim3(NCB, 2), BLOCK, 0, stream>>>(
        Af, Bf, Ag, Bp, wpred, wgt, partials);

    finalize_kernel<<<1, 128, 0, stream>>>(partials, out);
}